// Round 5
// baseline (292.805 us; speedup 1.0000x reference)
//
#include <hip/hip_runtime.h>
#include <hip/hip_bf16.h>
#include <math.h>

namespace {
constexpr int kD = 256;      // embed dim
constexpr int kDOUT = 256;   // out dim
constexpr int kNQ = 65536;   // num query nodes
constexpr int kE = 262144;   // edges
constexpr float kAlpha = 0.2f;
constexpr float kEps = 1e-12f;
}

typedef short bf16x8 __attribute__((ext_vector_type(8)));
typedef float f32x4 __attribute__((ext_vector_type(4)));

// c[j] = sum_k a[k][j] * a2[k]   (a is (DOUT, 2D) row-major; j in [0, 512))
__global__ void compute_c_kernel(const float* __restrict__ a,
                                 const float* __restrict__ a2,
                                 float* __restrict__ c) {
  const int j = blockIdx.x * blockDim.x + threadIdx.x;  // 0..511
  float s = 0.f;
#pragma unroll 8
  for (int k = 0; k < kDOUT; ++k) s = fmaf(a[k * (2 * kD) + j], a2[k], s);
  c[j] = s;
}

// zero count[] with a properly-sized grid
__global__ void zero_count_kernel(int4* __restrict__ count4) {
  count4[blockIdx.x * 256 + threadIdx.x] = int4{0, 0, 0, 0};
}

// trans (256x256 f32) -> bf16
__global__ void cvt_trans_kernel(const float* __restrict__ t, ushort* __restrict__ tb) {
  const int i = blockIdx.x * 256 + threadIdx.x;  // 4 elems each
  const float4 v = reinterpret_cast<const float4*>(t)[i];
  union { ushort4 u; __hip_bfloat16 h[4]; } p;
  p.h[0] = __float2bfloat16(v.x);
  p.h[1] = __float2bfloat16(v.y);
  p.h[2] = __float2bfloat16(v.z);
  p.h[3] = __float2bfloat16(v.w);
  reinterpret_cast<ushort4*>(tb)[i] = p.u;
}

// histogram of query_list into count[]
__global__ __launch_bounds__(256) void hist_kernel(const int* __restrict__ query_list,
                                                   int* __restrict__ count) {
  const int i = blockIdx.x * 256 + threadIdx.x;
  const int4 q = reinterpret_cast<const int4*>(query_list)[i];
  atomicAdd(&count[q.x], 1);
  atomicAdd(&count[q.y], 1);
  atomicAdd(&count[q.z], 1);
  atomicAdd(&count[q.w], 1);
}

// Single-block exclusive scan of count[NQ] -> offsets, cursor copy.
__global__ __launch_bounds__(1024) void scan_kernel(const int* __restrict__ count,
                                                    int* __restrict__ offsets,
                                                    int* __restrict__ cursor) {
  __shared__ int partial[1024];
  const int t = threadIdx.x;
  int4 loc[16];
#pragma unroll
  for (int i = 0; i < 16; ++i) loc[i] = reinterpret_cast<const int4*>(count)[t * 16 + i];
  int s = 0;
#pragma unroll
  for (int i = 0; i < 16; ++i) s += loc[i].x + loc[i].y + loc[i].z + loc[i].w;
  partial[t] = s;
  __syncthreads();
  for (int off = 1; off < 1024; off <<= 1) {
    int v = (t >= off) ? partial[t - off] : 0;
    __syncthreads();
    partial[t] += v;
    __syncthreads();
  }
  int run = partial[t] - s;
#pragma unroll
  for (int i = 0; i < 16; ++i) {
    const int4 v = loc[i];
    int4 o;
    o.x = run; run += v.x;
    o.y = run; run += v.y;
    o.z = run; run += v.z;
    o.w = run; run += v.w;
    reinterpret_cast<int4*>(offsets)[t * 16 + i] = o;
    reinterpret_cast<int4*>(cursor)[t * 16 + i] = o;
  }
  if (t == 1023) offsets[kNQ] = run;  // == E
}

// Scatter edge ids into CSR order.
__global__ __launch_bounds__(256) void scatter_kernel(const int* __restrict__ query_list,
                                                      int* __restrict__ cursor,
                                                      int* __restrict__ edge_ids) {
  const int edge = blockIdx.x * 256 + threadIdx.x;
  const int q = query_list[edge];
  const int pos = atomicAdd(&cursor[q], 1);
  edge_ids[pos] = edge;
}

// One wave per query; 4 edges processed per iteration by 16-lane sub-groups.
// Lane (g, l4): g = lane>>4 picks the edge slot, l4 = lane&15 covers floats
// [l4*16, l4*16+16) of the rows.  8 independent float4 loads per lane per
// iteration -> 8KB/wave in flight.  Tail groups clamp to last valid slot
// (duplicate load cache-served) with ev masked to 0.
__global__ __launch_bounds__(256) void fused_gather_kernel(
    const float* __restrict__ key_embed,
    const float* __restrict__ query_embed,
    const float* __restrict__ c,
    const int* __restrict__ offsets,
    const int* __restrict__ edge_ids,
    ushort* __restrict__ accb) {
  const int q = (blockIdx.x << 2) + (threadIdx.x >> 6);
  const int lane = threadIdx.x & 63;
  const int g = lane >> 4;
  const int l4 = lane & 15;
  const int s0 = offsets[q], s1 = offsets[q + 1];

  // per-lane chunk of c: c_k at floats [l4*16, +16), c_q at [256 + l4*16, +16)
  float4 ck[4], cq[4];
#pragma unroll
  for (int t = 0; t < 4; ++t) {
    ck[t] = reinterpret_cast<const float4*>(c)[l4 * 4 + t];
    cq[t] = reinterpret_cast<const float4*>(c)[64 + l4 * 4 + t];
  }

  f32x4 acc[4] = {};
  float rs = 0.f;

  for (int base = s0; base < s1; base += 64) {
    const int m = min(64, s1 - base);
    const int myid = (lane < m) ? edge_ids[base + lane] : 0;
    for (int j = 0; j < m; j += 4) {
      int slot = j + g;
      const bool active = slot < m;
      if (!active) slot = m - 1;                 // clamp: duplicate, cache-served
      const int edge = __shfl(myid, slot, 64);
      const float4* krow = reinterpret_cast<const float4*>(key_embed) + (size_t)edge * 64 + l4 * 4;
      const float4* qrow = reinterpret_cast<const float4*>(query_embed) + (size_t)edge * 64 + l4 * 4;
      float4 k4[4], q4[4];
#pragma unroll
      for (int t = 0; t < 4; ++t) k4[t] = krow[t];
#pragma unroll
      for (int t = 0; t < 4; ++t) q4[t] = qrow[t];
      float s = 0.f;
#pragma unroll
      for (int t = 0; t < 4; ++t) {
        s += k4[t].x * ck[t].x + k4[t].y * ck[t].y + k4[t].z * ck[t].z + k4[t].w * ck[t].w;
        s += q4[t].x * cq[t].x + q4[t].y * cq[t].y + q4[t].z * cq[t].z + q4[t].w * cq[t].w;
      }
#pragma unroll
      for (int off = 1; off < 16; off <<= 1) s += __shfl_xor(s, off, 64);
      const float p = (s > 0.f) ? s : kAlpha * s;   // leaky_relu
      const float ev = active ? __expf(-p) : 0.f;
      rs += ev;
#pragma unroll
      for (int t = 0; t < 4; ++t) {
        acc[t][0] = fmaf(ev, k4[t].x, acc[t][0]);
        acc[t][1] = fmaf(ev, k4[t].y, acc[t][1]);
        acc[t][2] = fmaf(ev, k4[t].z, acc[t][2]);
        acc[t][3] = fmaf(ev, k4[t].w, acc[t][3]);
      }
    }
  }

  // combine the 4 groups' partials: xor 16 then xor 32
#pragma unroll
  for (int t = 0; t < 4; ++t) {
#pragma unroll
    for (int i = 0; i < 4; ++i) {
      acc[t][i] += __shfl_xor(acc[t][i], 16, 64);
      acc[t][i] += __shfl_xor(acc[t][i], 32, 64);
    }
  }
  rs += __shfl_xor(rs, 16, 64);
  rs += __shfl_xor(rs, 32, 64);

  const float inv = 1.0f / ((rs == 0.f) ? kEps : rs);
  // lane (g,l4) writes cols [l4*16 + g*4, +4): 64 lanes x 8B = 512B coalesced
  union { ushort4 u; __hip_bfloat16 h[4]; } p;
  p.h[0] = __float2bfloat16(acc[g][0] * inv);
  p.h[1] = __float2bfloat16(acc[g][1] * inv);
  p.h[2] = __float2bfloat16(acc[g][2] * inv);
  p.h[3] = __float2bfloat16(acc[g][3] * inv);
  *reinterpret_cast<ushort4*>(accb + (size_t)q * kD + l4 * 16 + g * 4) = p.u;
}

// out = elu(A @ B^T).  A: (NQ,256) bf16 row-major (pre-normalized), B = trans bf16.
__global__ __launch_bounds__(256) void out_gemm_mfma_kernel(
    const ushort* __restrict__ A,
    const ushort* __restrict__ B,
    float* __restrict__ out) {
  const int wid = threadIdx.x >> 6;
  const int lane = threadIdx.x & 63;
  const int row0 = (blockIdx.x * 4 + wid) * 16;
  const int m = lane & 15;
  const int kb = (lane >> 4) * 8;

  f32x4 acc[16] = {};

  for (int kt = 0; kt < kD; kt += 32) {
    const bf16x8 af = *reinterpret_cast<const bf16x8*>(&A[(size_t)(row0 + m) * kD + kt + kb]);
#pragma unroll
    for (int nt = 0; nt < 16; ++nt) {
      const bf16x8 bf = *reinterpret_cast<const bf16x8*>(&B[(size_t)(nt * 16 + m) * kD + kt + kb]);
      acc[nt] = __builtin_amdgcn_mfma_f32_16x16x32_bf16(af, bf, acc[nt], 0, 0, 0);
    }
  }

#pragma unroll
  for (int nt = 0; nt < 16; ++nt) {
#pragma unroll
    for (int r = 0; r < 4; ++r) {
      const int row = row0 + (lane >> 4) * 4 + r;
      const int col = nt * 16 + (lane & 15);
      const float x = acc[nt][r];
      out[(size_t)row * kDOUT + col] = (x > 0.f) ? x : expm1f(x);
    }
  }
}

extern "C" void kernel_launch(void* const* d_in, const int* in_sizes, int n_in,
                              void* d_out, int out_size, void* d_ws, size_t ws_size,
                              hipStream_t stream) {
  // inputs: 0 key_list(int,E) [unused], 1 key_embed(f32,E*256), 2 query_list(int,E),
  //         3 query_embed(f32,E*256), 4 a(f32,256*512), 5 a_2(f32,256), 6 trans(f32,256*256)
  const float* key_embed = (const float*)d_in[1];
  const int* query_list = (const int*)d_in[2];
  const float* query_embed = (const float*)d_in[3];
  const float* a = (const float*)d_in[4];
  const float* a2 = (const float*)d_in[5];
  const float* trans = (const float*)d_in[6];
  float* out = (float*)d_out;

  // workspace layout (float units, all 16B-aligned):
  // c[512] | count[NQ] | offsets[NQ+4] | cursor[NQ] | edge_ids[E]
  // | acc_bf16[NQ*256 ushort] | trans_bf16[256*256 ushort]
  float* ws = (float*)d_ws;
  float* c = ws;
  int* count = (int*)(ws + 512);
  int* offsets = count + kNQ;
  int* cursor = offsets + kNQ + 4;
  int* edge_ids = cursor + kNQ;
  float* base2 = (float*)(edge_ids + kE);              // multiple of 4 floats
  ushort* accb = (ushort*)base2;                        // NQ*256 bf16
  ushort* transb = (ushort*)(base2 + kNQ * (kD / 2));   // 256*256 bf16

  zero_count_kernel<<<kNQ / 4 / 256, 256, 0, stream>>>((int4*)count);
  compute_c_kernel<<<2, 256, 0, stream>>>(a, a2, c);
  cvt_trans_kernel<<<kDOUT * kD / 4 / 256, 256, 0, stream>>>(trans, transb);
  hist_kernel<<<kE / 4 / 256, 256, 0, stream>>>(query_list, count);
  scan_kernel<<<1, 1024, 0, stream>>>(count, offsets, cursor);
  scatter_kernel<<<kE / 256, 256, 0, stream>>>(query_list, cursor, edge_ids);
  fused_gather_kernel<<<kNQ / 4, 256, 0, stream>>>(key_embed, query_embed, c, offsets,
                                                   edge_ids, accb);
  out_gemm_mfma_kernel<<<kNQ / 64, 256, 0, stream>>>(accb, transb, out);
}